// Round 2
// baseline (5424.682 us; speedup 1.0000x reference)
//
#include <hip/hip_runtime.h>
#include <hip/hip_bf16.h>
#include <stdint.h>

typedef __bf16 bf16;
typedef unsigned int uint;
typedef __attribute__((ext_vector_type(8))) __bf16 bf16x8;
typedef __attribute__((ext_vector_type(4))) float floatx4;

#define DEV static __device__ __forceinline__

typedef const __attribute__((address_space(1))) void* gptr_t;
typedef __attribute__((address_space(3))) void* lptr_t;

DEV void gload16(const void* g, void* l) {
  __builtin_amdgcn_global_load_lds((gptr_t)g, (lptr_t)l, 16, 0, 0);
}

DEV float2 b2f(uint u) {
  float2 r;
  r.x = __uint_as_float(u << 16);
  r.y = __uint_as_float(u & 0xffff0000u);
  return r;
}

// ---------------------------------------------------------------------------
// GEMM: C[M][N] (op)= A[M][K] * Bt[N][K]^T (+ bias[n])
// A, Bt bf16 row-major (lda=ldb=K). 128x128 tile, BK=32, 256 threads.
// MFMA 16x16x32 bf16 (m89-verified layouts).
// ---------------------------------------------------------------------------
#define EP_STORE_BF16 0
#define EP_STORE_F32  1
#define EP_ACCUM_F32  2
#define EP_RELU_BF16  3

template<int MODE>
__global__ __launch_bounds__(256, 2)
void gemm_bt(const bf16* __restrict__ A, const bf16* __restrict__ Bt,
             void* __restrict__ Cv, const float* __restrict__ bias,
             int K, int ldc)
{
  __shared__ bf16 As[128 * 32];
  __shared__ bf16 Bs[128 * 32];
  const int tid  = threadIdx.x;
  const int wave = tid >> 6;
  const int lane = tid & 63;
  const int m0 = blockIdx.y * 128;
  const int n0 = blockIdx.x * 128;
  const int wm = (wave >> 1) * 64;
  const int wn = (wave & 1) * 64;

  const int o1 = tid * 16;
  const int o2 = o1 + 4096;
  const int r1 = o1 >> 6, c1 = (o1 & 63) >> 1;
  const int r2 = o2 >> 6, c2 = (o2 & 63) >> 1;

  const bf16* Ab = A  + (size_t)m0 * K;
  const bf16* Bb = Bt + (size_t)n0 * K;

  floatx4 acc[4][4] = {};
  const int quad = lane >> 4;
  const int lrow = lane & 15;

  for (int k0 = 0; k0 < K; k0 += 32) {
    gload16(Ab + (size_t)r1 * K + (k0 + c1), As + (o1 >> 1));
    gload16(Ab + (size_t)r2 * K + (k0 + c2), As + (o2 >> 1));
    gload16(Bb + (size_t)r1 * K + (k0 + c1), Bs + (o1 >> 1));
    gload16(Bb + (size_t)r2 * K + (k0 + c2), Bs + (o2 >> 1));
    __syncthreads();

    bf16x8 af[4], bfr[4];
#pragma unroll
    for (int i = 0; i < 4; i++)
      af[i] = *(const bf16x8*)(As + (wm + i * 16 + lrow) * 32 + quad * 8);
#pragma unroll
    for (int j = 0; j < 4; j++)
      bfr[j] = *(const bf16x8*)(Bs + (wn + j * 16 + lrow) * 32 + quad * 8);
#pragma unroll
    for (int i = 0; i < 4; i++)
#pragma unroll
      for (int j = 0; j < 4; j++)
        acc[i][j] = __builtin_amdgcn_mfma_f32_16x16x32_bf16(af[i], bfr[j], acc[i][j], 0, 0, 0);
    __syncthreads();
  }

#pragma unroll
  for (int i = 0; i < 4; i++) {
    const int gm_base = m0 + wm + i * 16 + quad * 4;
#pragma unroll
    for (int j = 0; j < 4; j++) {
      const int gn = n0 + wn + j * 16 + lrow;
      const float bv = bias ? bias[gn] : 0.f;
#pragma unroll
      for (int r = 0; r < 4; r++) {
        const size_t idx = (size_t)(gm_base + r) * ldc + gn;
        float val = acc[i][j][r] + bv;
        if (MODE == EP_STORE_BF16)      ((bf16*)Cv)[idx] = (bf16)val;
        else if (MODE == EP_STORE_F32)  ((float*)Cv)[idx] = val;
        else if (MODE == EP_ACCUM_F32)  ((float*)Cv)[idx] += val;
        else { val = val > 0.f ? val : 0.f; ((bf16*)Cv)[idx] = (bf16)val; }
      }
    }
  }
}

// ---------------------------------------------------------------------------
// Transpose+cast: in fp32 [K][N] row-major, cols [n_off + gx*64 ...) ->
// out bf16 [Npiece][K] row-major (row = piece-local n).
// ---------------------------------------------------------------------------
__global__ __launch_bounds__(256)
void transpose_cast(const float* __restrict__ in, bf16* __restrict__ out,
                    int K, int N, int n_off)
{
  __shared__ float t[64][65];
  const int n0 = blockIdx.x * 64, k0 = blockIdx.y * 64;
  const int c  = threadIdx.x & 63;
  const int r4 = threadIdx.x >> 6;
#pragma unroll
  for (int p = 0; p < 16; p++) {
    const int r = p * 4 + r4;
    t[r][c] = in[(size_t)(k0 + r) * N + n_off + n0 + c];
  }
  __syncthreads();
#pragma unroll
  for (int p = 0; p < 16; p++) {
    const int r = p * 4 + r4;
    out[(size_t)(n0 + r) * K + k0 + c] = (bf16)t[c][r];
  }
}

// ---------------------------------------------------------------------------
// LayerNorm: x fp32 (rows x 768) -> h bf16, one wave per row.
// ---------------------------------------------------------------------------
__global__ __launch_bounds__(256)
void ln_kernel(const float* __restrict__ x, const float* __restrict__ sc,
               const float* __restrict__ bi, bf16* __restrict__ h)
{
  const int wave = threadIdx.x >> 6, lane = threadIdx.x & 63;
  const size_t row = (size_t)blockIdx.x * 4 + wave;
  const float* xr = x + row * 768;
  float4 v[3];
  float sum = 0.f;
#pragma unroll
  for (int i = 0; i < 3; i++) {
    v[i] = *(const float4*)(xr + i * 256 + lane * 4);
    sum += v[i].x + v[i].y + v[i].z + v[i].w;
  }
#pragma unroll
  for (int off = 32; off > 0; off >>= 1) sum += __shfl_xor(sum, off, 64);
  const float mean = sum * (1.f / 768.f);
  float sq = 0.f;
#pragma unroll
  for (int i = 0; i < 3; i++) {
    const float a = v[i].x - mean, b = v[i].y - mean;
    const float c = v[i].z - mean, d = v[i].w - mean;
    sq += a * a + b * b + c * c + d * d;
  }
#pragma unroll
  for (int off = 32; off > 0; off >>= 1) sq += __shfl_xor(sq, off, 64);
  const float inv = rsqrtf(sq * (1.f / 768.f) + 1e-5f);
  bf16* hr = h + row * 768;
#pragma unroll
  for (int i = 0; i < 3; i++) {
    const int p = i * 256 + lane * 4;
    const float4 s4 = *(const float4*)(sc + p);
    const float4 b4 = *(const float4*)(bi + p);
    union { bf16 b[4]; uint2 u; } pk;
    pk.b[0] = (bf16)((v[i].x - mean) * inv * s4.x + b4.x);
    pk.b[1] = (bf16)((v[i].y - mean) * inv * s4.y + b4.y);
    pk.b[2] = (bf16)((v[i].z - mean) * inv * s4.z + b4.z);
    pk.b[3] = (bf16)((v[i].w - mean) * inv * s4.w + b4.w);
    *(uint2*)(hr + p) = pk.u;
  }
}

// ---------------------------------------------------------------------------
// Attention: one block per (b, head). seq=80, DH=96.
// q: (rows,768) head slice; kv: (rows,1536) cols [k|v]. o may alias q.
// ---------------------------------------------------------------------------
__global__ __launch_bounds__(256)
void attn_kernel(const bf16* __restrict__ q, const bf16* __restrict__ kv,
                 bf16* __restrict__ o)
{
  __shared__ __align__(16) bf16 qs[80 * 96];
  __shared__ __align__(16) bf16 ks[80 * 96];
  __shared__ float ps[80 * 80];
  const int tid = threadIdx.x;
  const int b = blockIdx.x >> 3, hh = blockIdx.x & 7;
  const bf16* qbp = q  + (size_t)b * 80 * 768  + hh * 96;
  const bf16* kbp = kv + (size_t)b * 80 * 1536 + hh * 96;
  const bf16* vbp = kbp + 768;
  bf16* obp = o + (size_t)b * 80 * 768 + hh * 96;

  for (int i = tid; i < 3840; i += 256) {
    const int n = i / 48, dp = i - n * 48;
    ((uint*)qs)[i] = *(const uint*)(qbp + (size_t)n * 768  + dp * 2);
    ((uint*)ks)[i] = *(const uint*)(kbp + (size_t)n * 1536 + dp * 2);
  }
  __syncthreads();

  const float scale = 0.1020620726159658f;  // 1/sqrt(96)
  for (int i = tid; i < 6400; i += 256) {
    const int n = i / 80, m = i - n * 80;
    const uint* qp = (const uint*)(qs + n * 96);
    const uint* kp = (const uint*)(ks + m * 96);
    float s = 0.f;
#pragma unroll
    for (int d = 0; d < 48; d++) {
      const float2 a = b2f(qp[d]);
      const float2 c = b2f(kp[d]);
      s += a.x * c.x + a.y * c.y;
    }
    ps[i] = s * scale;
  }
  __syncthreads();

  if (tid < 80) {
    float* pr = ps + tid * 80;
    float mx = -1e30f;
    for (int m = 0; m < 80; m++) mx = fmaxf(mx, pr[m]);
    float sm = 0.f;
    for (int m = 0; m < 80; m++) { const float e = __expf(pr[m] - mx); pr[m] = e; sm += e; }
    const float inv = 1.f / sm;
    for (int m = 0; m < 80; m++) pr[m] *= inv;
  }
  __syncthreads();

  for (int i = tid; i < 3840; i += 256) {
    const int n = i / 48, dp = i - n * 48;
    const float* pr = ps + n * 80;
    float sx = 0.f, sy = 0.f;
#pragma unroll 16
    for (int m = 0; m < 80; m++) {
      const float2 v2 = b2f(*(const uint*)(vbp + (size_t)m * 1536 + dp * 2));
      const float p = pr[m];
      sx += p * v2.x; sy += p * v2.y;
    }
    union { bf16 h2[2]; uint u; } pk;
    pk.h2[0] = (bf16)sx; pk.h2[1] = (bf16)sy;
    *(uint*)(obp + (size_t)n * 768 + dp * 2) = pk.u;
  }
}

// ---------------------------------------------------------------------------
// utility kernels
// ---------------------------------------------------------------------------
__global__ __launch_bounds__(256)
void cast_f2b(const float* __restrict__ in, bf16* __restrict__ out, int n4)
{
  const int i = blockIdx.x * 256 + threadIdx.x;
  if (i >= n4) return;
  const float4 v = *(const float4*)(in + (size_t)i * 4);
  union { bf16 b[4]; uint2 u; } pk;
  pk.b[0] = (bf16)v.x; pk.b[1] = (bf16)v.y; pk.b[2] = (bf16)v.z; pk.b[3] = (bf16)v.w;
  *(uint2*)(out + (size_t)i * 4) = pk.u;
}

__global__ __launch_bounds__(256)
void prefix_fill(const float* __restrict__ pre, float* __restrict__ x)
{
  const size_t i = (size_t)blockIdx.x * 256 + threadIdx.x;
  const size_t b = i / 7680, r = i - b * 7680;
  *(float4*)(x + b * 61440 + 30720 + r * 4) = *(const float4*)(pre + r * 4);
}

__global__ __launch_bounds__(256)
void copy_out(const float* __restrict__ x, float* __restrict__ out)
{
  const size_t i = (size_t)blockIdx.x * 256 + threadIdx.x;
  const size_t b = i / 7680, r = i - b * 7680;
  *(float4*)(out + b * 30720 + r * 4) = *(const float4*)(x + b * 61440 + 30720 + r * 4);
}

// ---------------------------------------------------------------------------
extern "C" void kernel_launch(void* const* d_in, const int* in_sizes, int n_in,
                              void* d_out, int out_size, void* d_ws, size_t ws_size,
                              hipStream_t stream)
{
  (void)in_sizes; (void)n_in; (void)out_size;
  const float* latent = (const float*)d_in[0];
  const float* lin_w  = (const float*)d_in[1];
  const float* lin_b  = (const float*)d_in[2];
  const float* map_w  = (const float*)d_in[3];
  const float* map_b  = (const float*)d_in[4];
  const float* prefix = (const float*)d_in[5];
  const float* ln1_s  = (const float*)d_in[6];
  const float* ln1_b  = (const float*)d_in[7];
  const float* wq     = (const float*)d_in[8];
  const float* wkv    = (const float*)d_in[9];
  const float* wo     = (const float*)d_in[10];
  const float* bo     = (const float*)d_in[11];
  const float* ln2_s  = (const float*)d_in[12];
  const float* ln2_b  = (const float*)d_in[13];
  const float* w1     = (const float*)d_in[14];
  const float* b1     = (const float*)d_in[15];
  const float* w2     = (const float*)d_in[16];
  const float* b2     = (const float*)d_in[17];
  float* out = (float*)d_out;

  // --- workspace-size-adaptive config (ws_size constant -> graph-safe) ---
  int nchunk; bool wt_all;
  if      (ws_size >= 234000000ull) { nchunk = 1; wt_all = true;  }  // 232.8 MB
  else if (ws_size >= 168000000ull) { nchunk = 1; wt_all = false; }  // 166.7 MB
  else if (ws_size >= 121000000ull) { nchunk = 2; wt_all = false; }  // 119.5 MB
  else if (ws_size >=  97000000ull) { nchunk = 4; wt_all = false; }  //  95.9 MB
  else                              { nchunk = 8; wt_all = false; }  //  84.1 MB
  const int Rc = 20480 / nchunk;         // rows per chunk
  const int Bc = 256 / nchunk;           // batches per chunk
  const int npiece = (nchunk <= 2) ? 1 : (nchunk == 4 ? 2 : 4);
  const int pieceN = 30720 / npiece;

  char* wsp = (char*)d_ws;
  auto alloc = [&](size_t bytes) -> char* {
    char* p = wsp; wsp += (bytes + 255) & ~(size_t)255; return p;
  };
  float* xw    = (float*)alloc(62914560ull);            // residual fp32, all rows
  char*  region = alloc((size_t)4608 * Rc);             // h + kv (chunk) | map stage
  char*  wT     = alloc(wt_all ? 75497472ull : 9437184ull);

  // map-stage aliases inside region
  bf16* mapT = (bf16*)region;
  char* tail = region + (size_t)pieceN * 512 * 2;
  bf16* latv = (bf16*)tail;
  bf16* latb = (bf16*)(tail + 262144);
  bf16* linT = (bf16*)(tail + 524288);
  // layer-loop aliases inside region
  bf16* hbuf = (bf16*)region;
  bf16* kvb  = (bf16*)(region + (size_t)Rc * 1536);
  bf16* qb   = (bf16*)d_out;   // 31.46 MB needed max; out is 31.46 MB. dead until copy_out.

  const dim3 blk(256);

  // ---- input projection: lat = latent @ lin_w + b; x[:, :40] = lat @ map_w + b
  cast_f2b<<<128, blk, 0, stream>>>(latent, latv, 32768);
  transpose_cast<<<dim3(8, 8), blk, 0, stream>>>(lin_w, linT, 512, 512, 0);
  gemm_bt<EP_STORE_BF16><<<dim3(4, 2), blk, 0, stream>>>(latv, linT, latb, lin_b, 512, 512);
  for (int p = 0; p < npiece; p++) {
    transpose_cast<<<dim3(pieceN / 64, 8), blk, 0, stream>>>(map_w, mapT, 512, 30720, p * pieceN);
    gemm_bt<EP_STORE_F32><<<dim3(pieceN / 128, 2), blk, 0, stream>>>(
        latb, mapT, xw + p * pieceN, map_b + p * pieceN, 512, 61440);
  }
  prefix_fill<<<7680, blk, 0, stream>>>(prefix, xw);

  // ---- optional one-shot weight transposes
  if (wt_all) {
    for (int l = 0; l < 8; l++) {
      char* wl = wT + (size_t)l * 9437184;
      transpose_cast<<<dim3(12, 12), blk, 0, stream>>>(wq + (size_t)l * 589824,  (bf16*)wl,             768, 768, 0);
      transpose_cast<<<dim3(24, 12), blk, 0, stream>>>(wkv + (size_t)l * 1179648,(bf16*)(wl + 1179648), 768, 1536, 0);
      transpose_cast<<<dim3(12, 12), blk, 0, stream>>>(wo + (size_t)l * 589824,  (bf16*)(wl + 3538944), 768, 768, 0);
      transpose_cast<<<dim3(24, 12), blk, 0, stream>>>(w1 + (size_t)l * 1179648, (bf16*)(wl + 4718592), 768, 1536, 0);
      transpose_cast<<<dim3(12, 24), blk, 0, stream>>>(w2 + (size_t)l * 1179648, (bf16*)(wl + 7077888), 1536, 768, 0);
    }
  }

  // ---- transformer layers
  for (int l = 0; l < 8; l++) {
    char* wl = wT + (wt_all ? (size_t)l * 9437184 : 0);
    bf16* wqT  = (bf16*)wl;
    bf16* wkvT = (bf16*)(wl + 1179648);
    bf16* woT  = (bf16*)(wl + 3538944);
    bf16* w1T  = (bf16*)(wl + 4718592);
    bf16* w2T  = (bf16*)(wl + 7077888);
    if (!wt_all) {
      transpose_cast<<<dim3(12, 12), blk, 0, stream>>>(wq + (size_t)l * 589824,  wqT,  768, 768, 0);
      transpose_cast<<<dim3(24, 12), blk, 0, stream>>>(wkv + (size_t)l * 1179648,wkvT, 768, 1536, 0);
      transpose_cast<<<dim3(12, 12), blk, 0, stream>>>(wo + (size_t)l * 589824,  woT,  768, 768, 0);
      transpose_cast<<<dim3(24, 12), blk, 0, stream>>>(w1 + (size_t)l * 1179648, w1T,  768, 1536, 0);
      transpose_cast<<<dim3(12, 24), blk, 0, stream>>>(w2 + (size_t)l * 1179648, w2T,  1536, 768, 0);
    }
    for (int c = 0; c < nchunk; c++) {
      float* xc = xw + (size_t)c * Rc * 768;
      ln_kernel<<<Rc / 4, blk, 0, stream>>>(xc, ln1_s + l * 768, ln1_b + l * 768, hbuf);
      gemm_bt<EP_STORE_BF16><<<dim3(6, Rc / 128), blk, 0, stream>>>(hbuf, wqT, qb, nullptr, 768, 768);
      gemm_bt<EP_STORE_BF16><<<dim3(12, Rc / 128), blk, 0, stream>>>(hbuf, wkvT, kvb, nullptr, 768, 1536);
      attn_kernel<<<Bc * 8, blk, 0, stream>>>(qb, kvb, qb);
      gemm_bt<EP_ACCUM_F32><<<dim3(6, Rc / 128), blk, 0, stream>>>(qb, woT, xc, bo + l * 768, 768, 768);
      ln_kernel<<<Rc / 4, blk, 0, stream>>>(xc, ln2_s + l * 768, ln2_b + l * 768, hbuf);
      gemm_bt<EP_RELU_BF16><<<dim3(12, Rc / 128), blk, 0, stream>>>(hbuf, w1T, kvb, b1 + l * 1536, 768, 1536);
      gemm_bt<EP_ACCUM_F32><<<dim3(6, Rc / 128), blk, 0, stream>>>(kvb, w2T, xc, b2 + l * 768, 1536, 768);
    }
  }
  copy_out<<<7680, blk, 0, stream>>>(xw, out);
}

// Round 3
// 3828.448 us; speedup vs baseline: 1.4169x; 1.4169x over previous
//
#include <hip/hip_runtime.h>
#include <hip/hip_bf16.h>
#include <stdint.h>

typedef __bf16 bf16;
typedef unsigned int uint;
typedef __attribute__((ext_vector_type(8))) __bf16 bf16x8;
typedef __attribute__((ext_vector_type(4))) float floatx4;

#define DEV static __device__ __forceinline__

typedef const __attribute__((address_space(1))) void* gptr_t;
typedef __attribute__((address_space(3))) void* lptr_t;

DEV void gload16(const void* g, void* l) {
  __builtin_amdgcn_global_load_lds((gptr_t)g, (lptr_t)l, 16, 0, 0);
}

DEV uint f2b2(float x, float y) {
  union { bf16 h[2]; uint u; } pk;
  pk.h[0] = (bf16)x; pk.h[1] = (bf16)y;
  return pk.u;
}

// ---------------------------------------------------------------------------
// GEMM: C[M][N] (op)= A[M][K] * Bt[N][K]^T (+ bias[n])
// A, Bt bf16 row-major (lda=ldb=K). 128x128 tile, BK=32, 256 threads.
// MFMA 16x16x32 bf16 (m89-verified layouts).
// ---------------------------------------------------------------------------
#define EP_STORE_BF16 0
#define EP_STORE_F32  1
#define EP_ACCUM_F32  2
#define EP_RELU_BF16  3

template<int MODE>
__global__ __launch_bounds__(256, 2)
void gemm_bt(const bf16* __restrict__ A, const bf16* __restrict__ Bt,
             void* __restrict__ Cv, const float* __restrict__ bias,
             int K, int ldc)
{
  __shared__ bf16 As[128 * 32];
  __shared__ bf16 Bs[128 * 32];
  const int tid  = threadIdx.x;
  const int wave = tid >> 6;
  const int lane = tid & 63;
  const int m0 = blockIdx.y * 128;
  const int n0 = blockIdx.x * 128;
  const int wm = (wave >> 1) * 64;
  const int wn = (wave & 1) * 64;

  const int o1 = tid * 16;
  const int o2 = o1 + 4096;
  const int r1 = o1 >> 6, c1 = (o1 & 63) >> 1;
  const int r2 = o2 >> 6, c2 = (o2 & 63) >> 1;

  const bf16* Ab = A  + (size_t)m0 * K;
  const bf16* Bb = Bt + (size_t)n0 * K;

  floatx4 acc[4][4] = {};
  const int quad = lane >> 4;
  const int lrow = lane & 15;

  for (int k0 = 0; k0 < K; k0 += 32) {
    gload16(Ab + (size_t)r1 * K + (k0 + c1), As + (o1 >> 1));
    gload16(Ab + (size_t)r2 * K + (k0 + c2), As + (o2 >> 1));
    gload16(Bb + (size_t)r1 * K + (k0 + c1), Bs + (o1 >> 1));
    gload16(Bb + (size_t)r2 * K + (k0 + c2), Bs + (o2 >> 1));
    __syncthreads();

    bf16x8 af[4], bfr[4];
#pragma unroll
    for (int i = 0; i < 4; i++)
      af[i] = *(const bf16x8*)(As + (wm + i * 16 + lrow) * 32 + quad * 8);
#pragma unroll
    for (int j = 0; j < 4; j++)
      bfr[j] = *(const bf16x8*)(Bs + (wn + j * 16 + lrow) * 32 + quad * 8);
#pragma unroll
    for (int i = 0; i < 4; i++)
#pragma unroll
      for (int j = 0; j < 4; j++)
        acc[i][j] = __builtin_amdgcn_mfma_f32_16x16x32_bf16(af[i], bfr[j], acc[i][j], 0, 0, 0);
    __syncthreads();
  }

#pragma unroll
  for (int i = 0; i < 4; i++) {
    const int gm_base = m0 + wm + i * 16 + quad * 4;
#pragma unroll
    for (int j = 0; j < 4; j++) {
      const int gn = n0 + wn + j * 16 + lrow;
      const float bv = bias ? bias[gn] : 0.f;
#pragma unroll
      for (int r = 0; r < 4; r++) {
        const size_t idx = (size_t)(gm_base + r) * ldc + gn;
        float val = acc[i][j][r] + bv;
        if (MODE == EP_STORE_BF16)      ((bf16*)Cv)[idx] = (bf16)val;
        else if (MODE == EP_STORE_F32)  ((float*)Cv)[idx] = val;
        else if (MODE == EP_ACCUM_F32)  ((float*)Cv)[idx] += val;
        else { val = val > 0.f ? val : 0.f; ((bf16*)Cv)[idx] = (bf16)val; }
      }
    }
  }
}

// ---------------------------------------------------------------------------
// Transpose+cast: in fp32 [K][N] row-major, cols [n_off + gx*64 ...) ->
// out bf16 [Npiece][K] row-major (row = piece-local n).
// ---------------------------------------------------------------------------
__global__ __launch_bounds__(256)
void transpose_cast(const float* __restrict__ in, bf16* __restrict__ out,
                    int K, int N, int n_off)
{
  __shared__ float t[64][65];
  const int n0 = blockIdx.x * 64, k0 = blockIdx.y * 64;
  const int c  = threadIdx.x & 63;
  const int r4 = threadIdx.x >> 6;
#pragma unroll
  for (int p = 0; p < 16; p++) {
    const int r = p * 4 + r4;
    t[r][c] = in[(size_t)(k0 + r) * N + n_off + n0 + c];
  }
  __syncthreads();
#pragma unroll
  for (int p = 0; p < 16; p++) {
    const int r = p * 4 + r4;
    out[(size_t)(n0 + r) * K + k0 + c] = (bf16)t[c][r];
  }
}

// ---------------------------------------------------------------------------
// LayerNorm: x fp32 (rows x 768) -> h bf16, one wave per row.
// ---------------------------------------------------------------------------
__global__ __launch_bounds__(256)
void ln_kernel(const float* __restrict__ x, const float* __restrict__ sc,
               const float* __restrict__ bi, bf16* __restrict__ h)
{
  const int wave = threadIdx.x >> 6, lane = threadIdx.x & 63;
  const size_t row = (size_t)blockIdx.x * 4 + wave;
  const float* xr = x + row * 768;
  float4 v[3];
  float sum = 0.f;
#pragma unroll
  for (int i = 0; i < 3; i++) {
    v[i] = *(const float4*)(xr + i * 256 + lane * 4);
    sum += v[i].x + v[i].y + v[i].z + v[i].w;
  }
#pragma unroll
  for (int off = 32; off > 0; off >>= 1) sum += __shfl_xor(sum, off, 64);
  const float mean = sum * (1.f / 768.f);
  float sq = 0.f;
#pragma unroll
  for (int i = 0; i < 3; i++) {
    const float a = v[i].x - mean, b = v[i].y - mean;
    const float c = v[i].z - mean, d = v[i].w - mean;
    sq += a * a + b * b + c * c + d * d;
  }
#pragma unroll
  for (int off = 32; off > 0; off >>= 1) sq += __shfl_xor(sq, off, 64);
  const float inv = rsqrtf(sq * (1.f / 768.f) + 1e-5f);
  bf16* hr = h + row * 768;
#pragma unroll
  for (int i = 0; i < 3; i++) {
    const int p = i * 256 + lane * 4;
    const float4 s4 = *(const float4*)(sc + p);
    const float4 b4 = *(const float4*)(bi + p);
    union { bf16 b[4]; uint2 u; } pk;
    pk.b[0] = (bf16)((v[i].x - mean) * inv * s4.x + b4.x);
    pk.b[1] = (bf16)((v[i].y - mean) * inv * s4.y + b4.y);
    pk.b[2] = (bf16)((v[i].z - mean) * inv * s4.z + b4.z);
    pk.b[3] = (bf16)((v[i].w - mean) * inv * s4.w + b4.w);
    *(uint2*)(hr + p) = pk.u;
  }
}

// ---------------------------------------------------------------------------
// MFMA attention: one block per (b, head). seq=80, DH=96.
// q: (rows,768) head slice; kv: (rows,1536) cols [k|v]. o may alias q.
// LDS: Q[80][96]bf16 (aliased by P) | K[80][96]bf16 | Vt[96][96]bf16 | S[80][84]f32
// S = QK^T (25 tiles x 3 mfma), softmax rows, O = P*Vt (30 tiles x 3 mfma).
// ---------------------------------------------------------------------------
__global__ __launch_bounds__(256, 2)
void attn_kernel(const bf16* __restrict__ q, const bf16* __restrict__ kv,
                 bf16* __restrict__ o)
{
  __shared__ __align__(16) char smem[76032];
  bf16*  Qls = (bf16*)smem;            // 15360 B (aliased by P after softmax)
  bf16*  Kls = (bf16*)(smem + 15360);  // 15360 B
  bf16*  Vt  = (bf16*)(smem + 30720);  // 18432 B  [dh 96][seq 96 (pad 80..95=0)]
  float* S   = (float*)(smem + 49152); // 26880 B  [80][84]
  bf16*  P   = Qls;                    // [80][96], k 80..95 zero-padded

  const int tid = threadIdx.x;
  const int wave = tid >> 6, lane = tid & 63;
  const int quad = lane >> 4, lrow = lane & 15;
  const int b = blockIdx.x >> 3, hh = blockIdx.x & 7;
  const bf16* qbp = q  + (size_t)b * 80 * 768  + hh * 96;
  const bf16* kbp = kv + (size_t)b * 80 * 1536 + hh * 96;
  const bf16* vbp = kbp + 768;
  bf16* obp = o + (size_t)b * 80 * 768 + hh * 96;

  // stage Q, K row-major; V transposed: Vt[d][m] = V[m][d]
  for (int i = tid; i < 3840; i += 256) {
    const int n = i / 48, dp = i - n * 48;
    ((uint*)Qls)[i] = *(const uint*)(qbp + (size_t)n * 768  + dp * 2);
    ((uint*)Kls)[i] = *(const uint*)(kbp + (size_t)n * 1536 + dp * 2);
    union { uint u; bf16 h[2]; } v;
    v.u = *(const uint*)(vbp + (size_t)n * 1536 + dp * 2);
    Vt[(2 * dp)     * 96 + n] = v.h[0];
    Vt[(2 * dp + 1) * 96 + n] = v.h[1];
  }
  // zero Vt pad (seq 80..95) so P-pad x Vt-pad never makes NaN
  for (int i = tid; i < 768; i += 256) {
    const int n = i >> 3, kp = i & 7;
    ((uint*)Vt)[n * 48 + 40 + kp] = 0u;
  }
  __syncthreads();

  // S = scale * Q K^T  (tiles mi in [0,5), ni in [0,5))
  const float scale = 0.1020620726159658f;  // 1/sqrt(96)
  for (int t = wave; t < 25; t += 4) {
    const int mi = t / 5, ni = t - (t / 5) * 5;
    floatx4 acc = {};
#pragma unroll
    for (int ks = 0; ks < 3; ks++) {
      const bf16x8 a  = *(const bf16x8*)(Qls + (mi * 16 + lrow) * 96 + ks * 32 + quad * 8);
      const bf16x8 bb = *(const bf16x8*)(Kls + (ni * 16 + lrow) * 96 + ks * 32 + quad * 8);
      acc = __builtin_amdgcn_mfma_f32_16x16x32_bf16(a, bb, acc, 0, 0, 0);
    }
#pragma unroll
    for (int r = 0; r < 4; r++)
      S[(mi * 16 + quad * 4 + r) * 84 + ni * 16 + lrow] = acc[r] * scale;
  }
  __syncthreads();

  // softmax per row -> P bf16 (pad k 80..95 = 0); P aliases Q (barrier above)
  if (tid < 80) {
    float* sr = S + tid * 84;
    float mx = -1e30f;
    for (int m = 0; m < 80; m++) mx = fmaxf(mx, sr[m]);
    float sm = 0.f;
    for (int m = 0; m < 80; m++) { const float e = __expf(sr[m] - mx); sr[m] = e; sm += e; }
    const float inv = 1.f / sm;
    uint* pr = (uint*)(P + tid * 96);
    for (int m = 0; m < 40; m++) pr[m] = f2b2(sr[2 * m] * inv, sr[2 * m + 1] * inv);
    for (int m = 40; m < 48; m++) pr[m] = 0u;
  }
  __syncthreads();

  // O = P * V  (tiles mi in [0,5), ni in [0,6)), written straight to global
  for (int t = wave; t < 30; t += 4) {
    const int mi = t / 6, ni = t - (t / 6) * 6;
    floatx4 acc = {};
#pragma unroll
    for (int ks = 0; ks < 3; ks++) {
      const bf16x8 a  = *(const bf16x8*)(P  + (mi * 16 + lrow) * 96 + ks * 32 + quad * 8);
      const bf16x8 bb = *(const bf16x8*)(Vt + (ni * 16 + lrow) * 96 + ks * 32 + quad * 8);
      acc = __builtin_amdgcn_mfma_f32_16x16x32_bf16(a, bb, acc, 0, 0, 0);
    }
#pragma unroll
    for (int r = 0; r < 4; r++)
      obp[(size_t)(mi * 16 + quad * 4 + r) * 768 + ni * 16 + lrow] = (bf16)acc[r];
  }
}

// ---------------------------------------------------------------------------
// utility kernels
// ---------------------------------------------------------------------------
__global__ __launch_bounds__(256)
void cast_f2b(const float* __restrict__ in, bf16* __restrict__ out, int n4)
{
  const int i = blockIdx.x * 256 + threadIdx.x;
  if (i >= n4) return;
  const float4 v = *(const float4*)(in + (size_t)i * 4);
  union { bf16 b[4]; uint2 u; } pk;
  pk.b[0] = (bf16)v.x; pk.b[1] = (bf16)v.y; pk.b[2] = (bf16)v.z; pk.b[3] = (bf16)v.w;
  *(uint2*)(out + (size_t)i * 4) = pk.u;
}

__global__ __launch_bounds__(256)
void prefix_fill(const float* __restrict__ pre, float* __restrict__ x)
{
  const size_t i = (size_t)blockIdx.x * 256 + threadIdx.x;
  const size_t b = i / 7680, r = i - b * 7680;
  *(float4*)(x + b * 61440 + 30720 + r * 4) = *(const float4*)(pre + r * 4);
}

__global__ __launch_bounds__(256)
void copy_out(const float* __restrict__ x, float* __restrict__ out)
{
  const size_t i = (size_t)blockIdx.x * 256 + threadIdx.x;
  const size_t b = i / 7680, r = i - b * 7680;
  *(float4*)(out + b * 30720 + r * 4) = *(const float4*)(x + b * 61440 + 30720 + r * 4);
}

// ---------------------------------------------------------------------------
extern "C" void kernel_launch(void* const* d_in, const int* in_sizes, int n_in,
                              void* d_out, int out_size, void* d_ws, size_t ws_size,
                              hipStream_t stream)
{
  (void)in_sizes; (void)n_in; (void)out_size;
  const float* latent = (const float*)d_in[0];
  const float* lin_w  = (const float*)d_in[1];
  const float* lin_b  = (const float*)d_in[2];
  const float* map_w  = (const float*)d_in[3];
  const float* map_b  = (const float*)d_in[4];
  const float* prefix = (const float*)d_in[5];
  const float* ln1_s  = (const float*)d_in[6];
  const float* ln1_b  = (const float*)d_in[7];
  const float* wq     = (const float*)d_in[8];
  const float* wkv    = (const float*)d_in[9];
  const float* wo     = (const float*)d_in[10];
  const float* bo     = (const float*)d_in[11];
  const float* ln2_s  = (const float*)d_in[12];
  const float* ln2_b  = (const float*)d_in[13];
  const float* w1     = (const float*)d_in[14];
  const float* b1     = (const float*)d_in[15];
  const float* w2     = (const float*)d_in[16];
  const float* b2     = (const float*)d_in[17];
  float* out = (float*)d_out;

  // --- workspace-size-adaptive config (ws_size constant -> graph-safe) ---
  int nchunk; bool wt_all;
  if      (ws_size >= 234000000ull) { nchunk = 1; wt_all = true;  }  // 232.8 MB
  else if (ws_size >= 168000000ull) { nchunk = 1; wt_all = false; }  // 166.7 MB
  else if (ws_size >= 121000000ull) { nchunk = 2; wt_all = false; }  // 119.5 MB
  else if (ws_size >=  97000000ull) { nchunk = 4; wt_all = false; }  //  95.9 MB
  else                              { nchunk = 8; wt_all = false; }  //  84.1 MB
  const int Rc = 20480 / nchunk;         // rows per chunk
  const int Bc = 256 / nchunk;           // batches per chunk
  const int npiece = (nchunk <= 2) ? 1 : (nchunk == 4 ? 2 : 4);
  const int pieceN = 30720 / npiece;

  char* wsp = (char*)d_ws;
  auto alloc = [&](size_t bytes) -> char* {
    char* p = wsp; wsp += (bytes + 255) & ~(size_t)255; return p;
  };
  float* xw    = (float*)alloc(62914560ull);            // residual fp32, all rows
  char*  region = alloc((size_t)4608 * Rc);             // h + kv (chunk) | map stage
  char*  wT     = alloc(wt_all ? 75497472ull : 9437184ull);

  // map-stage aliases inside region
  bf16* mapT = (bf16*)region;
  char* tail = region + (size_t)pieceN * 512 * 2;
  bf16* latv = (bf16*)tail;
  bf16* latb = (bf16*)(tail + 262144);
  bf16* linT = (bf16*)(tail + 524288);
  // layer-loop aliases inside region
  bf16* hbuf = (bf16*)region;
  bf16* kvb  = (bf16*)(region + (size_t)Rc * 1536);
  bf16* qb   = (bf16*)d_out;   // 31.46 MB needed max; out is 31.46 MB. dead until copy_out.

  const dim3 blk(256);

  // ---- input projection: lat = latent @ lin_w + b; x[:, :40] = lat @ map_w + b
  cast_f2b<<<128, blk, 0, stream>>>(latent, latv, 32768);
  transpose_cast<<<dim3(8, 8), blk, 0, stream>>>(lin_w, linT, 512, 512, 0);
  gemm_bt<EP_STORE_BF16><<<dim3(4, 2), blk, 0, stream>>>(latv, linT, latb, lin_b, 512, 512);
  for (int p = 0; p < npiece; p++) {
    transpose_cast<<<dim3(pieceN / 64, 8), blk, 0, stream>>>(map_w, mapT, 512, 30720, p * pieceN);
    gemm_bt<EP_STORE_F32><<<dim3(pieceN / 128, 2), blk, 0, stream>>>(
        latb, mapT, xw + p * pieceN, map_b + p * pieceN, 512, 61440);
  }
  prefix_fill<<<7680, blk, 0, stream>>>(prefix, xw);

  // ---- optional one-shot weight transposes
  if (wt_all) {
    for (int l = 0; l < 8; l++) {
      char* wl = wT + (size_t)l * 9437184;
      transpose_cast<<<dim3(12, 12), blk, 0, stream>>>(wq + (size_t)l * 589824,  (bf16*)wl,             768, 768, 0);
      transpose_cast<<<dim3(24, 12), blk, 0, stream>>>(wkv + (size_t)l * 1179648,(bf16*)(wl + 1179648), 768, 1536, 0);
      transpose_cast<<<dim3(12, 12), blk, 0, stream>>>(wo + (size_t)l * 589824,  (bf16*)(wl + 3538944), 768, 768, 0);
      transpose_cast<<<dim3(24, 12), blk, 0, stream>>>(w1 + (size_t)l * 1179648, (bf16*)(wl + 4718592), 768, 1536, 0);
      transpose_cast<<<dim3(12, 24), blk, 0, stream>>>(w2 + (size_t)l * 1179648, (bf16*)(wl + 7077888), 1536, 768, 0);
    }
  }

  // ---- transformer layers
  for (int l = 0; l < 8; l++) {
    char* wl = wT + (wt_all ? (size_t)l * 9437184 : 0);
    bf16* wqT  = (bf16*)wl;
    bf16* wkvT = (bf16*)(wl + 1179648);
    bf16* woT  = (bf16*)(wl + 3538944);
    bf16* w1T  = (bf16*)(wl + 4718592);
    bf16* w2T  = (bf16*)(wl + 7077888);
    if (!wt_all) {
      transpose_cast<<<dim3(12, 12), blk, 0, stream>>>(wq + (size_t)l * 589824,  wqT,  768, 768, 0);
      transpose_cast<<<dim3(24, 12), blk, 0, stream>>>(wkv + (size_t)l * 1179648,wkvT, 768, 1536, 0);
      transpose_cast<<<dim3(12, 12), blk, 0, stream>>>(wo + (size_t)l * 589824,  woT,  768, 768, 0);
      transpose_cast<<<dim3(24, 12), blk, 0, stream>>>(w1 + (size_t)l * 1179648, w1T,  768, 1536, 0);
      transpose_cast<<<dim3(12, 24), blk, 0, stream>>>(w2 + (size_t)l * 1179648, w2T,  1536, 768, 0);
    }
    for (int c = 0; c < nchunk; c++) {
      float* xc = xw + (size_t)c * Rc * 768;
      ln_kernel<<<Rc / 4, blk, 0, stream>>>(xc, ln1_s + l * 768, ln1_b + l * 768, hbuf);
      gemm_bt<EP_STORE_BF16><<<dim3(6, Rc / 128), blk, 0, stream>>>(hbuf, wqT, qb, nullptr, 768, 768);
      gemm_bt<EP_STORE_BF16><<<dim3(12, Rc / 128), blk, 0, stream>>>(hbuf, wkvT, kvb, nullptr, 768, 1536);
      attn_kernel<<<Bc * 8, blk, 0, stream>>>(qb, kvb, qb);
      gemm_bt<EP_ACCUM_F32><<<dim3(6, Rc / 128), blk, 0, stream>>>(qb, woT, xc, bo + l * 768, 768, 768);
      ln_kernel<<<Rc / 4, blk, 0, stream>>>(xc, ln2_s + l * 768, ln2_b + l * 768, hbuf);
      gemm_bt<EP_RELU_BF16><<<dim3(12, Rc / 128), blk, 0, stream>>>(hbuf, w1T, kvb, b1 + l * 1536, 768, 1536);
      gemm_bt<EP_ACCUM_F32><<<dim3(6, Rc / 128), blk, 0, stream>>>(kvb, w2T, xc, b2 + l * 768, 1536, 768);
    }
  }
  copy_out<<<7680, blk, 0, stream>>>(xw, out);
}

// Round 4
// 3448.412 us; speedup vs baseline: 1.5731x; 1.1102x over previous
//
#include <hip/hip_runtime.h>
#include <hip/hip_bf16.h>
#include <stdint.h>

typedef __bf16 bf16;
typedef unsigned int uint;
typedef __attribute__((ext_vector_type(8))) __bf16 bf16x8;
typedef __attribute__((ext_vector_type(4))) float floatx4;

#define DEV static __device__ __forceinline__

typedef const __attribute__((address_space(1))) void* gptr_t;
typedef __attribute__((address_space(3))) void* lptr_t;

DEV void gload16(const void* g, void* l) {
  __builtin_amdgcn_global_load_lds((gptr_t)g, (lptr_t)l, 16, 0, 0);
}

DEV uint f2b2(float x, float y) {
  union { bf16 h[2]; uint u; } pk;
  pk.h[0] = (bf16)x; pk.h[1] = (bf16)y;
  return pk.u;
}

// ---------------------------------------------------------------------------
// GEMM: C[M][N] (op)= A[M][K] * Bt[N][K]^T (+ bias[n])
// A, Bt bf16 row-major (lda=ldb=K). 128x128 tile, BK=32, 256 threads.
// MFMA 16x16x32 bf16 (m89-verified layouts).
// XCD-aware swizzle: co-A-panel blocks share flat%8 -> one XCD's L2.
// ---------------------------------------------------------------------------
#define EP_STORE_BF16 0
#define EP_STORE_F32  1
#define EP_ACCUM_F32  2
#define EP_RELU_BF16  3
#define EP_QKV        4

template<int MODE>
__global__ __launch_bounds__(256, 2)
void gemm_bt(const bf16* __restrict__ A, const bf16* __restrict__ Bt,
             void* __restrict__ Cv, void* __restrict__ Cv2,
             const float* __restrict__ bias, int K, int ldc)
{
  __shared__ bf16 As[128 * 32];
  __shared__ bf16 Bs[128 * 32];
  const int tid  = threadIdx.x;
  const int wave = tid >> 6;
  const int lane = tid & 63;

  // XCD-aware swizzle (identity when gridDim.y % 8 != 0)
  int bx = blockIdx.x, by = blockIdx.y;
  const int gx = (int)gridDim.x, gy = (int)gridDim.y;
  if ((gy & 7) == 0) {
    const int flat = by * gx + bx;
    const int xcd  = flat & 7;
    const int s    = flat >> 3;
    const int rows_per = gy >> 3;
    const int m_local  = s / gx;
    bx = s - m_local * gx;
    by = xcd * rows_per + m_local;
  }
  const int m0 = by * 128;
  const int n0 = bx * 128;
  const int wm = (wave >> 1) * 64;
  const int wn = (wave & 1) * 64;

  const int o1 = tid * 16;
  const int o2 = o1 + 4096;
  const int r1 = o1 >> 6, c1 = (o1 & 63) >> 1;
  const int r2 = o2 >> 6, c2 = (o2 & 63) >> 1;

  const bf16* Ab = A  + (size_t)m0 * K;
  const bf16* Bb = Bt + (size_t)n0 * K;

  floatx4 acc[4][4] = {};
  const int quad = lane >> 4;
  const int lrow = lane & 15;

  for (int k0 = 0; k0 < K; k0 += 32) {
    gload16(Ab + (size_t)r1 * K + (k0 + c1), As + (o1 >> 1));
    gload16(Ab + (size_t)r2 * K + (k0 + c2), As + (o2 >> 1));
    gload16(Bb + (size_t)r1 * K + (k0 + c1), Bs + (o1 >> 1));
    gload16(Bb + (size_t)r2 * K + (k0 + c2), Bs + (o2 >> 1));
    __syncthreads();

    bf16x8 af[4], bfr[4];
#pragma unroll
    for (int i = 0; i < 4; i++)
      af[i] = *(const bf16x8*)(As + (wm + i * 16 + lrow) * 32 + quad * 8);
#pragma unroll
    for (int j = 0; j < 4; j++)
      bfr[j] = *(const bf16x8*)(Bs + (wn + j * 16 + lrow) * 32 + quad * 8);
#pragma unroll
    for (int i = 0; i < 4; i++)
#pragma unroll
      for (int j = 0; j < 4; j++)
        acc[i][j] = __builtin_amdgcn_mfma_f32_16x16x32_bf16(af[i], bfr[j], acc[i][j], 0, 0, 0);
    __syncthreads();
  }

#pragma unroll
  for (int i = 0; i < 4; i++) {
    const int gm_base = m0 + wm + i * 16 + quad * 4;
#pragma unroll
    for (int j = 0; j < 4; j++) {
      const int gn = n0 + wn + j * 16 + lrow;
      const float bv = (MODE != EP_QKV && bias) ? bias[gn] : 0.f;
#pragma unroll
      for (int r = 0; r < 4; r++) {
        const int gm = gm_base + r;
        float val = acc[i][j][r] + bv;
        if (MODE == EP_QKV) {
          if (gn < 768) ((bf16*)Cv)[(size_t)gm * 768 + gn] = (bf16)val;
          else          ((bf16*)Cv2)[(size_t)gm * 1536 + (gn - 768)] = (bf16)val;
        } else {
          const size_t idx = (size_t)gm * ldc + gn;
          if (MODE == EP_STORE_BF16)      ((bf16*)Cv)[idx] = (bf16)val;
          else if (MODE == EP_STORE_F32)  ((float*)Cv)[idx] = val;
          else if (MODE == EP_ACCUM_F32)  ((float*)Cv)[idx] += val;
          else { val = val > 0.f ? val : 0.f; ((bf16*)Cv)[idx] = (bf16)val; }
        }
      }
    }
  }
}

// ---------------------------------------------------------------------------
// Transpose+cast: in fp32 [K][N] row-major, cols [n_off + gx*64 ...) ->
// out bf16 [Npiece][K] row-major (row = piece-local n).
// ---------------------------------------------------------------------------
__global__ __launch_bounds__(256)
void transpose_cast(const float* __restrict__ in, bf16* __restrict__ out,
                    int K, int N, int n_off)
{
  __shared__ float t[64][65];
  const int n0 = blockIdx.x * 64, k0 = blockIdx.y * 64;
  const int c  = threadIdx.x & 63;
  const int r4 = threadIdx.x >> 6;
#pragma unroll
  for (int p = 0; p < 16; p++) {
    const int r = p * 4 + r4;
    t[r][c] = in[(size_t)(k0 + r) * N + n_off + n0 + c];
  }
  __syncthreads();
#pragma unroll
  for (int p = 0; p < 16; p++) {
    const int r = p * 4 + r4;
    out[(size_t)(n0 + r) * K + k0 + c] = (bf16)t[c][r];
  }
}

// ---------------------------------------------------------------------------
// LayerNorm: x fp32 (rows x 768) -> h bf16, one wave per row.
// ---------------------------------------------------------------------------
__global__ __launch_bounds__(256)
void ln_kernel(const float* __restrict__ x, const float* __restrict__ sc,
               const float* __restrict__ bi, bf16* __restrict__ h)
{
  const int wave = threadIdx.x >> 6, lane = threadIdx.x & 63;
  const size_t row = (size_t)blockIdx.x * 4 + wave;
  const float* xr = x + row * 768;
  float4 v[3];
  float sum = 0.f;
#pragma unroll
  for (int i = 0; i < 3; i++) {
    v[i] = *(const float4*)(xr + i * 256 + lane * 4);
    sum += v[i].x + v[i].y + v[i].z + v[i].w;
  }
#pragma unroll
  for (int off = 32; off > 0; off >>= 1) sum += __shfl_xor(sum, off, 64);
  const float mean = sum * (1.f / 768.f);
  float sq = 0.f;
#pragma unroll
  for (int i = 0; i < 3; i++) {
    const float a = v[i].x - mean, b = v[i].y - mean;
    const float c = v[i].z - mean, d = v[i].w - mean;
    sq += a * a + b * b + c * c + d * d;
  }
#pragma unroll
  for (int off = 32; off > 0; off >>= 1) sq += __shfl_xor(sq, off, 64);
  const float inv = rsqrtf(sq * (1.f / 768.f) + 1e-5f);
  bf16* hr = h + row * 768;
#pragma unroll
  for (int i = 0; i < 3; i++) {
    const int p = i * 256 + lane * 4;
    const float4 s4 = *(const float4*)(sc + p);
    const float4 b4 = *(const float4*)(bi + p);
    union { bf16 b[4]; uint2 u; } pk;
    pk.b[0] = (bf16)((v[i].x - mean) * inv * s4.x + b4.x);
    pk.b[1] = (bf16)((v[i].y - mean) * inv * s4.y + b4.y);
    pk.b[2] = (bf16)((v[i].z - mean) * inv * s4.z + b4.z);
    pk.b[3] = (bf16)((v[i].w - mean) * inv * s4.w + b4.w);
    *(uint2*)(hr + p) = pk.u;
  }
}

// ---------------------------------------------------------------------------
// MFMA attention: one block per (b, head). seq=80, DH=96.
// q: (rows,768) head slice; kv: (rows,1536) cols [k|v]. o may alias q.
// LDS: Q[80][96]bf16 (aliased by P) | K[80][96]bf16 | Vt[96][96]bf16 | S[80][84]f32
// ---------------------------------------------------------------------------
__global__ __launch_bounds__(256, 2)
void attn_kernel(const bf16* __restrict__ q, const bf16* __restrict__ kv,
                 bf16* __restrict__ o)
{
  __shared__ __align__(16) char smem[76032];
  bf16*  Qls = (bf16*)smem;            // 15360 B (aliased by P after softmax)
  bf16*  Kls = (bf16*)(smem + 15360);  // 15360 B
  bf16*  Vt  = (bf16*)(smem + 30720);  // 18432 B  [dh 96][seq 96 (pad 80..95=0)]
  float* S   = (float*)(smem + 49152); // 26880 B  [80][84]
  bf16*  P   = Qls;                    // [80][96], k 80..95 zero-padded

  const int tid = threadIdx.x;
  const int wave = tid >> 6, lane = tid & 63;
  const int quad = lane >> 4, lrow = lane & 15;
  const int b = blockIdx.x >> 3, hh = blockIdx.x & 7;
  const bf16* qbp = q  + (size_t)b * 80 * 768  + hh * 96;
  const bf16* kbp = kv + (size_t)b * 80 * 1536 + hh * 96;
  const bf16* vbp = kbp + 768;
  bf16* obp = o + (size_t)b * 80 * 768 + hh * 96;

  for (int i = tid; i < 3840; i += 256) {
    const int n = i / 48, dp = i - n * 48;
    ((uint*)Qls)[i] = *(const uint*)(qbp + (size_t)n * 768  + dp * 2);
    ((uint*)Kls)[i] = *(const uint*)(kbp + (size_t)n * 1536 + dp * 2);
    union { uint u; bf16 h[2]; } v;
    v.u = *(const uint*)(vbp + (size_t)n * 1536 + dp * 2);
    Vt[(2 * dp)     * 96 + n] = v.h[0];
    Vt[(2 * dp + 1) * 96 + n] = v.h[1];
  }
  for (int i = tid; i < 768; i += 256) {
    const int n = i >> 3, kp = i & 7;
    ((uint*)Vt)[n * 48 + 40 + kp] = 0u;
  }
  __syncthreads();

  const float scale = 0.1020620726159658f;  // 1/sqrt(96)
  for (int t = wave; t < 25; t += 4) {
    const int mi = t / 5, ni = t - (t / 5) * 5;
    floatx4 acc = {};
#pragma unroll
    for (int ks = 0; ks < 3; ks++) {
      const bf16x8 a  = *(const bf16x8*)(Qls + (mi * 16 + lrow) * 96 + ks * 32 + quad * 8);
      const bf16x8 bb = *(const bf16x8*)(Kls + (ni * 16 + lrow) * 96 + ks * 32 + quad * 8);
      acc = __builtin_amdgcn_mfma_f32_16x16x32_bf16(a, bb, acc, 0, 0, 0);
    }
#pragma unroll
    for (int r = 0; r < 4; r++)
      S[(mi * 16 + quad * 4 + r) * 84 + ni * 16 + lrow] = acc[r] * scale;
  }
  __syncthreads();

  if (tid < 80) {
    float* sr = S + tid * 84;
    float mx = -1e30f;
    for (int m = 0; m < 80; m++) mx = fmaxf(mx, sr[m]);
    float sm = 0.f;
    for (int m = 0; m < 80; m++) { const float e = __expf(sr[m] - mx); sr[m] = e; sm += e; }
    const float inv = 1.f / sm;
    uint* pr = (uint*)(P + tid * 96);
    for (int m = 0; m < 40; m++) pr[m] = f2b2(sr[2 * m] * inv, sr[2 * m + 1] * inv);
    for (int m = 40; m < 48; m++) pr[m] = 0u;
  }
  __syncthreads();

  for (int t = wave; t < 30; t += 4) {
    const int mi = t / 6, ni = t - (t / 6) * 6;
    floatx4 acc = {};
#pragma unroll
    for (int ks = 0; ks < 3; ks++) {
      const bf16x8 a  = *(const bf16x8*)(P  + (mi * 16 + lrow) * 96 + ks * 32 + quad * 8);
      const bf16x8 bb = *(const bf16x8*)(Vt + (ni * 16 + lrow) * 96 + ks * 32 + quad * 8);
      acc = __builtin_amdgcn_mfma_f32_16x16x32_bf16(a, bb, acc, 0, 0, 0);
    }
#pragma unroll
    for (int r = 0; r < 4; r++)
      obp[(size_t)(mi * 16 + quad * 4 + r) * 768 + ni * 16 + lrow] = (bf16)acc[r];
  }
}

// ---------------------------------------------------------------------------
// utility kernels
// ---------------------------------------------------------------------------
__global__ __launch_bounds__(256)
void cast_f2b(const float* __restrict__ in, bf16* __restrict__ out, int n4)
{
  const int i = blockIdx.x * 256 + threadIdx.x;
  if (i >= n4) return;
  const float4 v = *(const float4*)(in + (size_t)i * 4);
  union { bf16 b[4]; uint2 u; } pk;
  pk.b[0] = (bf16)v.x; pk.b[1] = (bf16)v.y; pk.b[2] = (bf16)v.z; pk.b[3] = (bf16)v.w;
  *(uint2*)(out + (size_t)i * 4) = pk.u;
}

__global__ __launch_bounds__(256)
void prefix_fill(const float* __restrict__ pre, float* __restrict__ x)
{
  const size_t i = (size_t)blockIdx.x * 256 + threadIdx.x;
  const size_t b = i / 7680, r = i - b * 7680;
  *(float4*)(x + b * 61440 + 30720 + r * 4) = *(const float4*)(pre + r * 4);
}

__global__ __launch_bounds__(256)
void copy_out(const float* __restrict__ x, float* __restrict__ out)
{
  const size_t i = (size_t)blockIdx.x * 256 + threadIdx.x;
  const size_t b = i / 7680, r = i - b * 7680;
  *(float4*)(out + b * 30720 + r * 4) = *(const float4*)(x + b * 61440 + 30720 + r * 4);
}

// ---------------------------------------------------------------------------
extern "C" void kernel_launch(void* const* d_in, const int* in_sizes, int n_in,
                              void* d_out, int out_size, void* d_ws, size_t ws_size,
                              hipStream_t stream)
{
  (void)in_sizes; (void)n_in; (void)out_size;
  const float* latent = (const float*)d_in[0];
  const float* lin_w  = (const float*)d_in[1];
  const float* lin_b  = (const float*)d_in[2];
  const float* map_w  = (const float*)d_in[3];
  const float* map_b  = (const float*)d_in[4];
  const float* prefix = (const float*)d_in[5];
  const float* ln1_s  = (const float*)d_in[6];
  const float* ln1_b  = (const float*)d_in[7];
  const float* wq     = (const float*)d_in[8];
  const float* wkv    = (const float*)d_in[9];
  const float* wo     = (const float*)d_in[10];
  const float* bo     = (const float*)d_in[11];
  const float* ln2_s  = (const float*)d_in[12];
  const float* ln2_b  = (const float*)d_in[13];
  const float* w1     = (const float*)d_in[14];
  const float* b1     = (const float*)d_in[15];
  const float* w2     = (const float*)d_in[16];
  const float* b2     = (const float*)d_in[17];
  float* out = (float*)d_out;

  // --- workspace-size-adaptive config (ws_size constant -> graph-safe) ---
  int nchunk; bool wt_all;
  if      (ws_size >= 234000000ull) { nchunk = 1; wt_all = true;  }  // 232.8 MB
  else if (ws_size >= 168000000ull) { nchunk = 1; wt_all = false; }  // 166.7 MB
  else if (ws_size >= 121000000ull) { nchunk = 2; wt_all = false; }  // 119.5 MB
  else if (ws_size >=  97000000ull) { nchunk = 4; wt_all = false; }  //  95.9 MB
  else                              { nchunk = 8; wt_all = false; }  //  84.1 MB
  const int Rc = 20480 / nchunk;         // rows per chunk
  const int Bc = 256 / nchunk;           // batches per chunk
  const int npiece = (nchunk <= 2) ? 1 : (nchunk == 4 ? 2 : 4);
  const int pieceN = 30720 / npiece;

  char* wsp = (char*)d_ws;
  auto alloc = [&](size_t bytes) -> char* {
    char* p = wsp; wsp += (bytes + 255) & ~(size_t)255; return p;
  };
  float* xw    = (float*)alloc(62914560ull);            // residual fp32, all rows
  char*  region = alloc((size_t)4608 * Rc);             // h + kv (chunk) | map stage
  char*  wT     = alloc(wt_all ? 75497472ull : 9437184ull);

  // map-stage aliases inside region
  bf16* mapT = (bf16*)region;
  char* tail = region + (size_t)pieceN * 512 * 2;
  bf16* latv = (bf16*)tail;
  bf16* latb = (bf16*)(tail + 262144);
  bf16* linT = (bf16*)(tail + 524288);
  // layer-loop aliases inside region
  bf16* hbuf = (bf16*)region;
  bf16* kvb  = (bf16*)(region + (size_t)Rc * 1536);
  bf16* qb   = (bf16*)d_out;   // dead until copy_out; holds q / attn-out

  const dim3 blk(256);

  // ---- input projection
  cast_f2b<<<128, blk, 0, stream>>>(latent, latv, 32768);
  transpose_cast<<<dim3(8, 8), blk, 0, stream>>>(lin_w, linT, 512, 512, 0);
  gemm_bt<EP_STORE_BF16><<<dim3(4, 2), blk, 0, stream>>>(latv, linT, latb, nullptr, lin_b, 512, 512);
  for (int p = 0; p < npiece; p++) {
    transpose_cast<<<dim3(pieceN / 64, 8), blk, 0, stream>>>(map_w, mapT, 512, 30720, p * pieceN);
    gemm_bt<EP_STORE_F32><<<dim3(pieceN / 128, 2), blk, 0, stream>>>(
        latb, mapT, xw + p * pieceN, nullptr, map_b + p * pieceN, 512, 61440);
  }
  prefix_fill<<<7680, blk, 0, stream>>>(prefix, xw);

  // ---- optional one-shot weight transposes
  if (wt_all) {
    for (int l = 0; l < 8; l++) {
      char* wl = wT + (size_t)l * 9437184;
      transpose_cast<<<dim3(12, 12), blk, 0, stream>>>(wq + (size_t)l * 589824,  (bf16*)wl,             768, 768, 0);
      transpose_cast<<<dim3(24, 12), blk, 0, stream>>>(wkv + (size_t)l * 1179648,(bf16*)(wl + 1179648), 768, 1536, 0);
      transpose_cast<<<dim3(12, 12), blk, 0, stream>>>(wo + (size_t)l * 589824,  (bf16*)(wl + 3538944), 768, 768, 0);
      transpose_cast<<<dim3(24, 12), blk, 0, stream>>>(w1 + (size_t)l * 1179648, (bf16*)(wl + 4718592), 768, 1536, 0);
      transpose_cast<<<dim3(12, 24), blk, 0, stream>>>(w2 + (size_t)l * 1179648, (bf16*)(wl + 7077888), 1536, 768, 0);
    }
  }

  // ---- transformer layers
  for (int l = 0; l < 8; l++) {
    char* wl = wT + (wt_all ? (size_t)l * 9437184 : 0);
    bf16* wqT  = (bf16*)wl;                    // wkvT contiguous after wqT
    bf16* woT  = (bf16*)(wl + 3538944);
    bf16* w1T  = (bf16*)(wl + 4718592);
    bf16* w2T  = (bf16*)(wl + 7077888);
    if (!wt_all) {
      transpose_cast<<<dim3(12, 12), blk, 0, stream>>>(wq + (size_t)l * 589824,  wqT,  768, 768, 0);
      transpose_cast<<<dim3(24, 12), blk, 0, stream>>>(wkv + (size_t)l * 1179648,(bf16*)(wl + 1179648), 768, 1536, 0);
      transpose_cast<<<dim3(12, 12), blk, 0, stream>>>(wo + (size_t)l * 589824,  woT,  768, 768, 0);
      transpose_cast<<<dim3(24, 12), blk, 0, stream>>>(w1 + (size_t)l * 1179648, w1T,  768, 1536, 0);
      transpose_cast<<<dim3(12, 24), blk, 0, stream>>>(w2 + (size_t)l * 1179648, w2T,  1536, 768, 0);
    }
    for (int c = 0; c < nchunk; c++) {
      float* xc = xw + (size_t)c * Rc * 768;
      ln_kernel<<<Rc / 4, blk, 0, stream>>>(xc, ln1_s + l * 768, ln1_b + l * 768, hbuf);
      gemm_bt<EP_QKV><<<dim3(18, Rc / 128), blk, 0, stream>>>(
          hbuf, wqT, qb, kvb, nullptr, 768, 0);
      attn_kernel<<<Bc * 8, blk, 0, stream>>>(qb, kvb, qb);
      gemm_bt<EP_ACCUM_F32><<<dim3(6, Rc / 128), blk, 0, stream>>>(
          qb, woT, xc, nullptr, bo + l * 768, 768, 768);
      ln_kernel<<<Rc / 4, blk, 0, stream>>>(xc, ln2_s + l * 768, ln2_b + l * 768, hbuf);
      gemm_bt<EP_RELU_BF16><<<dim3(12, Rc / 128), blk, 0, stream>>>(
          hbuf, w1T, kvb, nullptr, b1 + l * 1536, 768, 1536);
      gemm_bt<EP_ACCUM_F32><<<dim3(6, Rc / 128), blk, 0, stream>>>(
          kvb, w2T, xc, nullptr, b2 + l * 768, 1536, 768);
    }
  }
  copy_out<<<7680, blk, 0, stream>>>(xw, out);
}

// Round 5
// 3020.334 us; speedup vs baseline: 1.7961x; 1.1417x over previous
//
#include <hip/hip_runtime.h>
#include <hip/hip_bf16.h>
#include <stdint.h>

typedef __bf16 bf16;
typedef unsigned int uint;
typedef __attribute__((ext_vector_type(8))) __bf16 bf16x8;
typedef __attribute__((ext_vector_type(4))) float floatx4;

#define DEV static __device__ __forceinline__

typedef const __attribute__((address_space(1))) void* gptr_t;
typedef __attribute__((address_space(3))) void* lptr_t;

DEV void gload16(const void* g, void* l) {
  __builtin_amdgcn_global_load_lds((gptr_t)g, (lptr_t)l, 16, 0, 0);
}

DEV uint f2b2(float x, float y) {
  union { bf16 h[2]; uint u; } pk;
  pk.h[0] = (bf16)x; pk.h[1] = (bf16)y;
  return pk.u;
}

// ---------------------------------------------------------------------------
// GEMM: C[M][N] (op)= A[M][K] * Bt[N][K]^T (+ bias[n])
// A, Bt bf16 row-major (lda=ldb=K, K % 64 == 0). 128x128 tile, BK=64,
// 256 threads, MFMA 16x16x32 bf16 (m89 layouts).
// LDS tiles XOR-8 swizzled: elem (r,c) at byte r*128 + ((c/8)^(r&7))*16
//  -> global_load_lds staging stays contiguous (only source addr permuted),
//     ds_read_b128 frag reads hit all 32 banks (2 lanes/bank = free).
// XCD-aware block swizzle: co-A-panel blocks share flat%8 -> one XCD's L2.
// ---------------------------------------------------------------------------
#define EP_STORE_BF16 0
#define EP_STORE_F32  1
#define EP_ACCUM_F32  2
#define EP_RELU_BF16  3
#define EP_QKV        4

template<int MODE>
__global__ __launch_bounds__(256, 4)
void gemm_bt(const bf16* __restrict__ A, const bf16* __restrict__ Bt,
             void* __restrict__ Cv, void* __restrict__ Cv2,
             const float* __restrict__ bias, int K, int ldc)
{
  __shared__ bf16 As[128 * 64];
  __shared__ bf16 Bs[128 * 64];
  const int tid  = threadIdx.x;
  const int wave = tid >> 6;
  const int lane = tid & 63;

  // XCD-aware swizzle (identity when gridDim.y % 8 != 0)
  int bx = blockIdx.x, by = blockIdx.y;
  const int gx = (int)gridDim.x, gy = (int)gridDim.y;
  if ((gy & 7) == 0) {
    const int flat = by * gx + bx;
    const int xcd  = flat & 7;
    const int s    = flat >> 3;
    const int rows_per = gy >> 3;
    const int m_local  = s / gx;
    bx = s - m_local * gx;
    by = xcd * rows_per + m_local;
  }
  const int m0 = by * 128;
  const int n0 = bx * 128;
  const int wm = (wave >> 1) * 64;
  const int wn = (wave & 1) * 64;

  // staging: thread t covers LDS bytes t*16 (+ j*4096 per call j=0..3)
  const int rA = tid >> 3;                 // local row 0..31 (call adds j*32)
  const int lc = (tid & 7) ^ (rA & 7);     // logical 16B-chunk (const: 32%8==0)
  const bf16* Asrc = A  + (size_t)(m0 + rA) * K + lc * 8;
  const bf16* Bsrc = Bt + (size_t)(n0 + rA) * K + lc * 8;
  bf16* Adst = As + tid * 8;               // element offset (16B per thread)
  bf16* Bdst = Bs + tid * 8;

  floatx4 acc[4][4] = {};
  const int quad = lane >> 4;
  const int lrow = lane & 15;
  const int xr   = lrow & 7;               // row-phase for read-side XOR

  for (int k0 = 0; k0 < K; k0 += 64) {
#pragma unroll
    for (int j = 0; j < 4; j++) {
      gload16(Asrc + k0 + (size_t)j * 32 * K, Adst + j * 2048);
      gload16(Bsrc + k0 + (size_t)j * 32 * K, Bdst + j * 2048);
    }
    __syncthreads();

#pragma unroll
    for (int ks = 0; ks < 2; ks++) {
      bf16x8 af[4], bfr[4];
#pragma unroll
      for (int i = 0; i < 4; i++)
        af[i] = *(const bf16x8*)(As + (wm + i * 16 + lrow) * 64 + ((ks * 4 + quad) ^ xr) * 8);
#pragma unroll
      for (int j = 0; j < 4; j++)
        bfr[j] = *(const bf16x8*)(Bs + (wn + j * 16 + lrow) * 64 + ((ks * 4 + quad) ^ xr) * 8);
#pragma unroll
      for (int i = 0; i < 4; i++)
#pragma unroll
        for (int j = 0; j < 4; j++)
          acc[i][j] = __builtin_amdgcn_mfma_f32_16x16x32_bf16(af[i], bfr[j], acc[i][j], 0, 0, 0);
    }
    __syncthreads();
  }

#pragma unroll
  for (int i = 0; i < 4; i++) {
    const int gm_base = m0 + wm + i * 16 + quad * 4;
#pragma unroll
    for (int j = 0; j < 4; j++) {
      const int gn = n0 + wn + j * 16 + lrow;
      const float bv = (MODE != EP_QKV && bias) ? bias[gn] : 0.f;
#pragma unroll
      for (int r = 0; r < 4; r++) {
        const int gm = gm_base + r;
        float val = acc[i][j][r] + bv;
        if (MODE == EP_QKV) {
          if (gn < 768) ((bf16*)Cv)[(size_t)gm * 768 + gn] = (bf16)val;
          else          ((bf16*)Cv2)[(size_t)gm * 1536 + (gn - 768)] = (bf16)val;
        } else {
          const size_t idx = (size_t)gm * ldc + gn;
          if (MODE == EP_STORE_BF16)      ((bf16*)Cv)[idx] = (bf16)val;
          else if (MODE == EP_STORE_F32)  ((float*)Cv)[idx] = val;
          else if (MODE == EP_ACCUM_F32)  ((float*)Cv)[idx] += val;
          else { val = val > 0.f ? val : 0.f; ((bf16*)Cv)[idx] = (bf16)val; }
        }
      }
    }
  }
}

// ---------------------------------------------------------------------------
// Transpose+cast: in fp32 [K][N] row-major, cols [n_off + gx*64 ...) ->
// out bf16 [Npiece][K] row-major (row = piece-local n).
// ---------------------------------------------------------------------------
__global__ __launch_bounds__(256)
void transpose_cast(const float* __restrict__ in, bf16* __restrict__ out,
                    int K, int N, int n_off)
{
  __shared__ float t[64][65];
  const int n0 = blockIdx.x * 64, k0 = blockIdx.y * 64;
  const int c  = threadIdx.x & 63;
  const int r4 = threadIdx.x >> 6;
#pragma unroll
  for (int p = 0; p < 16; p++) {
    const int r = p * 4 + r4;
    t[r][c] = in[(size_t)(k0 + r) * N + n_off + n0 + c];
  }
  __syncthreads();
#pragma unroll
  for (int p = 0; p < 16; p++) {
    const int r = p * 4 + r4;
    out[(size_t)(n0 + r) * K + k0 + c] = (bf16)t[c][r];
  }
}

// ---------------------------------------------------------------------------
// LayerNorm: x fp32 (rows x 768) -> h bf16, one wave per row.
// ---------------------------------------------------------------------------
__global__ __launch_bounds__(256)
void ln_kernel(const float* __restrict__ x, const float* __restrict__ sc,
               const float* __restrict__ bi, bf16* __restrict__ h)
{
  const int wave = threadIdx.x >> 6, lane = threadIdx.x & 63;
  const size_t row = (size_t)blockIdx.x * 4 + wave;
  const float* xr = x + row * 768;
  float4 v[3];
  float sum = 0.f;
#pragma unroll
  for (int i = 0; i < 3; i++) {
    v[i] = *(const float4*)(xr + i * 256 + lane * 4);
    sum += v[i].x + v[i].y + v[i].z + v[i].w;
  }
#pragma unroll
  for (int off = 32; off > 0; off >>= 1) sum += __shfl_xor(sum, off, 64);
  const float mean = sum * (1.f / 768.f);
  float sq = 0.f;
#pragma unroll
  for (int i = 0; i < 3; i++) {
    const float a = v[i].x - mean, b = v[i].y - mean;
    const float c = v[i].z - mean, d = v[i].w - mean;
    sq += a * a + b * b + c * c + d * d;
  }
#pragma unroll
  for (int off = 32; off > 0; off >>= 1) sq += __shfl_xor(sq, off, 64);
  const float inv = rsqrtf(sq * (1.f / 768.f) + 1e-5f);
  bf16* hr = h + row * 768;
#pragma unroll
  for (int i = 0; i < 3; i++) {
    const int p = i * 256 + lane * 4;
    const float4 s4 = *(const float4*)(sc + p);
    const float4 b4 = *(const float4*)(bi + p);
    union { bf16 b[4]; uint2 u; } pk;
    pk.b[0] = (bf16)((v[i].x - mean) * inv * s4.x + b4.x);
    pk.b[1] = (bf16)((v[i].y - mean) * inv * s4.y + b4.y);
    pk.b[2] = (bf16)((v[i].z - mean) * inv * s4.z + b4.z);
    pk.b[3] = (bf16)((v[i].w - mean) * inv * s4.w + b4.w);
    *(uint2*)(hr + p) = pk.u;
  }
}

// ---------------------------------------------------------------------------
// MFMA attention: one block per (b, head). seq=80, DH=96.
// q: (rows,768) head slice; kv: (rows,1536) cols [k|v]. o may alias q.
// LDS: Q[80][96]bf16 (aliased by P) | K[80][96]bf16 | Vt[96][96]bf16 | S[80][84]f32
// ---------------------------------------------------------------------------
__global__ __launch_bounds__(256, 2)
void attn_kernel(const bf16* __restrict__ q, const bf16* __restrict__ kv,
                 bf16* __restrict__ o)
{
  __shared__ __align__(16) char smem[76032];
  bf16*  Qls = (bf16*)smem;            // 15360 B (aliased by P after softmax)
  bf16*  Kls = (bf16*)(smem + 15360);  // 15360 B
  bf16*  Vt  = (bf16*)(smem + 30720);  // 18432 B  [dh 96][seq 96 (pad 80..95=0)]
  float* S   = (float*)(smem + 49152); // 26880 B  [80][84]
  bf16*  P   = Qls;                    // [80][96], k 80..95 zero-padded

  const int tid = threadIdx.x;
  const int wave = tid >> 6, lane = tid & 63;
  const int quad = lane >> 4, lrow = lane & 15;
  const int b = blockIdx.x >> 3, hh = blockIdx.x & 7;
  const bf16* qbp = q  + (size_t)b * 80 * 768  + hh * 96;
  const bf16* kbp = kv + (size_t)b * 80 * 1536 + hh * 96;
  const bf16* vbp = kbp + 768;
  bf16* obp = o + (size_t)b * 80 * 768 + hh * 96;

  for (int i = tid; i < 3840; i += 256) {
    const int n = i / 48, dp = i - n * 48;
    ((uint*)Qls)[i] = *(const uint*)(qbp + (size_t)n * 768  + dp * 2);
    ((uint*)Kls)[i] = *(const uint*)(kbp + (size_t)n * 1536 + dp * 2);
    union { uint u; bf16 h[2]; } v;
    v.u = *(const uint*)(vbp + (size_t)n * 1536 + dp * 2);
    Vt[(2 * dp)     * 96 + n] = v.h[0];
    Vt[(2 * dp + 1) * 96 + n] = v.h[1];
  }
  for (int i = tid; i < 768; i += 256) {
    const int n = i >> 3, kp = i & 7;
    ((uint*)Vt)[n * 48 + 40 + kp] = 0u;
  }
  __syncthreads();

  const float scale = 0.1020620726159658f;  // 1/sqrt(96)
  for (int t = wave; t < 25; t += 4) {
    const int mi = t / 5, ni = t - (t / 5) * 5;
    floatx4 acc = {};
#pragma unroll
    for (int ks = 0; ks < 3; ks++) {
      const bf16x8 a  = *(const bf16x8*)(Qls + (mi * 16 + lrow) * 96 + ks * 32 + quad * 8);
      const bf16x8 bb = *(const bf16x8*)(Kls + (ni * 16 + lrow) * 96 + ks * 32 + quad * 8);
      acc = __builtin_amdgcn_mfma_f32_16x16x32_bf16(a, bb, acc, 0, 0, 0);
    }
#pragma unroll
    for (int r = 0; r < 4; r++)
      S[(mi * 16 + quad * 4 + r) * 84 + ni * 16 + lrow] = acc[r] * scale;
  }
  __syncthreads();

  if (tid < 80) {
    float* sr = S + tid * 84;
    float mx = -1e30f;
    for (int m = 0; m < 80; m++) mx = fmaxf(mx, sr[m]);
    float sm = 0.f;
    for (int m = 0; m < 80; m++) { const float e = __expf(sr[m] - mx); sr[m] = e; sm += e; }
    const float inv = 1.f / sm;
    uint* pr = (uint*)(P + tid * 96);
    for (int m = 0; m < 40; m++) pr[m] = f2b2(sr[2 * m] * inv, sr[2 * m + 1] * inv);
    for (int m = 40; m < 48; m++) pr[m] = 0u;
  }
  __syncthreads();

  for (int t = wave; t < 30; t += 4) {
    const int mi = t / 6, ni = t - (t / 6) * 6;
    floatx4 acc = {};
#pragma unroll
    for (int ks = 0; ks < 3; ks++) {
      const bf16x8 a  = *(const bf16x8*)(P  + (mi * 16 + lrow) * 96 + ks * 32 + quad * 8);
      const bf16x8 bb = *(const bf16x8*)(Vt + (ni * 16 + lrow) * 96 + ks * 32 + quad * 8);
      acc = __builtin_amdgcn_mfma_f32_16x16x32_bf16(a, bb, acc, 0, 0, 0);
    }
#pragma unroll
    for (int r = 0; r < 4; r++)
      obp[(size_t)(mi * 16 + quad * 4 + r) * 768 + ni * 16 + lrow] = (bf16)acc[r];
  }
}

// ---------------------------------------------------------------------------
// utility kernels
// ---------------------------------------------------------------------------
__global__ __launch_bounds__(256)
void cast_f2b(const float* __restrict__ in, bf16* __restrict__ out, int n4)
{
  const int i = blockIdx.x * 256 + threadIdx.x;
  if (i >= n4) return;
  const float4 v = *(const float4*)(in + (size_t)i * 4);
  union { bf16 b[4]; uint2 u; } pk;
  pk.b[0] = (bf16)v.x; pk.b[1] = (bf16)v.y; pk.b[2] = (bf16)v.z; pk.b[3] = (bf16)v.w;
  *(uint2*)(out + (size_t)i * 4) = pk.u;
}

__global__ __launch_bounds__(256)
void prefix_fill(const float* __restrict__ pre, float* __restrict__ x)
{
  const size_t i = (size_t)blockIdx.x * 256 + threadIdx.x;
  const size_t b = i / 7680, r = i - b * 7680;
  *(float4*)(x + b * 61440 + 30720 + r * 4) = *(const float4*)(pre + r * 4);
}

__global__ __launch_bounds__(256)
void copy_out(const float* __restrict__ x, float* __restrict__ out)
{
  const size_t i = (size_t)blockIdx.x * 256 + threadIdx.x;
  const size_t b = i / 7680, r = i - b * 7680;
  *(float4*)(out + b * 30720 + r * 4) = *(const float4*)(x + b * 61440 + 30720 + r * 4);
}

// ---------------------------------------------------------------------------
extern "C" void kernel_launch(void* const* d_in, const int* in_sizes, int n_in,
                              void* d_out, int out_size, void* d_ws, size_t ws_size,
                              hipStream_t stream)
{
  (void)in_sizes; (void)n_in; (void)out_size;
  const float* latent = (const float*)d_in[0];
  const float* lin_w  = (const float*)d_in[1];
  const float* lin_b  = (const float*)d_in[2];
  const float* map_w  = (const float*)d_in[3];
  const float* map_b  = (const float*)d_in[4];
  const float* prefix = (const float*)d_in[5];
  const float* ln1_s  = (const float*)d_in[6];
  const float* ln1_b  = (const float*)d_in[7];
  const float* wq     = (const float*)d_in[8];
  const float* wkv    = (const float*)d_in[9];
  const float* wo     = (const float*)d_in[10];
  const float* bo     = (const float*)d_in[11];
  const float* ln2_s  = (const float*)d_in[12];
  const float* ln2_b  = (const float*)d_in[13];
  const float* w1     = (const float*)d_in[14];
  const float* b1     = (const float*)d_in[15];
  const float* w2     = (const float*)d_in[16];
  const float* b2     = (const float*)d_in[17];
  float* out = (float*)d_out;

  // --- workspace-size-adaptive config (ws_size constant -> graph-safe) ---
  int nchunk; bool wt_all;
  if      (ws_size >= 234000000ull) { nchunk = 1; wt_all = true;  }  // 232.8 MB
  else if (ws_size >= 168000000ull) { nchunk = 1; wt_all = false; }  // 166.7 MB
  else if (ws_size >= 121000000ull) { nchunk = 2; wt_all = false; }  // 119.5 MB
  else if (ws_size >=  97000000ull) { nchunk = 4; wt_all = false; }  //  95.9 MB
  else                              { nchunk = 8; wt_all = false; }  //  84.1 MB
  const int Rc = 20480 / nchunk;         // rows per chunk
  const int Bc = 256 / nchunk;           // batches per chunk
  const int npiece = (nchunk <= 2) ? 1 : (nchunk == 4 ? 2 : 4);
  const int pieceN = 30720 / npiece;

  char* wsp = (char*)d_ws;
  auto alloc = [&](size_t bytes) -> char* {
    char* p = wsp; wsp += (bytes + 255) & ~(size_t)255; return p;
  };
  float* xw    = (float*)alloc(62914560ull);            // residual fp32, all rows
  char*  region = alloc((size_t)4608 * Rc);             // h + kv (chunk) | map stage
  char*  wT     = alloc(wt_all ? 75497472ull : 9437184ull);

  // map-stage aliases inside region
  bf16* mapT = (bf16*)region;
  char* tail = region + (size_t)pieceN * 512 * 2;
  bf16* latv = (bf16*)tail;
  bf16* latb = (bf16*)(tail + 262144);
  bf16* linT = (bf16*)(tail + 524288);
  // layer-loop aliases inside region
  bf16* hbuf = (bf16*)region;
  bf16* kvb  = (bf16*)(region + (size_t)Rc * 1536);
  bf16* qb   = (bf16*)d_out;   // dead until copy_out; holds q / attn-out

  const dim3 blk(256);

  // ---- input projection
  cast_f2b<<<128, blk, 0, stream>>>(latent, latv, 32768);
  transpose_cast<<<dim3(8, 8), blk, 0, stream>>>(lin_w, linT, 512, 512, 0);
  gemm_bt<EP_STORE_BF16><<<dim3(4, 2), blk, 0, stream>>>(latv, linT, latb, nullptr, lin_b, 512, 512);
  for (int p = 0; p < npiece; p++) {
    transpose_cast<<<dim3(pieceN / 64, 8), blk, 0, stream>>>(map_w, mapT, 512, 30720, p * pieceN);
    gemm_bt<EP_STORE_F32><<<dim3(pieceN / 128, 2), blk, 0, stream>>>(
        latb, mapT, xw + p * pieceN, nullptr, map_b + p * pieceN, 512, 61440);
  }
  prefix_fill<<<7680, blk, 0, stream>>>(prefix, xw);

  // ---- optional one-shot weight transposes
  if (wt_all) {
    for (int l = 0; l < 8; l++) {
      char* wl = wT + (size_t)l * 9437184;
      transpose_cast<<<dim3(12, 12), blk, 0, stream>>>(wq + (size_t)l * 589824,  (bf16*)wl,             768, 768, 0);
      transpose_cast<<<dim3(24, 12), blk, 0, stream>>>(wkv + (size_t)l * 1179648,(bf16*)(wl + 1179648), 768, 1536, 0);
      transpose_cast<<<dim3(12, 12), blk, 0, stream>>>(wo + (size_t)l * 589824,  (bf16*)(wl + 3538944), 768, 768, 0);
      transpose_cast<<<dim3(24, 12), blk, 0, stream>>>(w1 + (size_t)l * 1179648, (bf16*)(wl + 4718592), 768, 1536, 0);
      transpose_cast<<<dim3(12, 24), blk, 0, stream>>>(w2 + (size_t)l * 1179648, (bf16*)(wl + 7077888), 1536, 768, 0);
    }
  }

  // ---- transformer layers
  for (int l = 0; l < 8; l++) {
    char* wl = wT + (wt_all ? (size_t)l * 9437184 : 0);
    bf16* wqT  = (bf16*)wl;                    // wkvT contiguous after wqT
    bf16* woT  = (bf16*)(wl + 3538944);
    bf16* w1T  = (bf16*)(wl + 4718592);
    bf16* w2T  = (bf16*)(wl + 7077888);
    if (!wt_all) {
      transpose_cast<<<dim3(12, 12), blk, 0, stream>>>(wq + (size_t)l * 589824,  wqT,  768, 768, 0);
      transpose_cast<<<dim3(24, 12), blk, 0, stream>>>(wkv + (size_t)l * 1179648,(bf16*)(wl + 1179648), 768, 1536, 0);
      transpose_cast<<<dim3(12, 12), blk, 0, stream>>>(wo + (size_t)l * 589824,  woT,  768, 768, 0);
      transpose_cast<<<dim3(24, 12), blk, 0, stream>>>(w1 + (size_t)l * 1179648, w1T,  768, 1536, 0);
      transpose_cast<<<dim3(12, 24), blk, 0, stream>>>(w2 + (size_t)l * 1179648, w2T,  1536, 768, 0);
    }
    for (int c = 0; c < nchunk; c++) {
      float* xc = xw + (size_t)c * Rc * 768;
      ln_kernel<<<Rc / 4, blk, 0, stream>>>(xc, ln1_s + l * 768, ln1_b + l * 768, hbuf);
      gemm_bt<EP_QKV><<<dim3(18, Rc / 128), blk, 0, stream>>>(
          hbuf, wqT, qb, kvb, nullptr, 768, 0);
      attn_kernel<<<Bc * 8, blk, 0, stream>>>(qb, kvb, qb);
      gemm_bt<EP_ACCUM_F32><<<dim3(6, Rc / 128), blk, 0, stream>>>(
          qb, woT, xc, nullptr, bo + l * 768, 768, 768);
      ln_kernel<<<Rc / 4, blk, 0, stream>>>(xc, ln2_s + l * 768, ln2_b + l * 768, hbuf);
      gemm_bt<EP_RELU_BF16><<<dim3(12, Rc / 128), blk, 0, stream>>>(
          hbuf, w1T, kvb, nullptr, b1 + l * 1536, 768, 1536);
      gemm_bt<EP_ACCUM_F32><<<dim3(6, Rc / 128), blk, 0, stream>>>(
          kvb, w2T, xc, nullptr, b2 + l * 768, 1536, 768);
    }
  }
  copy_out<<<7680, blk, 0, stream>>>(xw, out);
}